// Round 1
// baseline (380.631 us; speedup 1.0000x reference)
//
#include <hip/hip_runtime.h>
#include <math.h>

typedef _Float16 f16;
typedef _Float16 half8 __attribute__((ext_vector_type(8)));
typedef float floatx16 __attribute__((ext_vector_type(16)));
typedef unsigned int u32;

#define HW_     3136
#define NPC     50176.0f
#define PB      3364            // 58*58 padded pixels per image
#define PPLANE  53824           // 16 images * PB (chunks per k2-plane)
#define ASTRIDE (2 * PPLANE * 16)   // bytes between s-steps (k2 += 2) = 1722368

// LDS scalar swizzle (conflict-free both phases; same as final_kernel, verified)
#define SW(c, px) (((px) + ((c) >> 2) + ((c) & 3) * 8) & 63)

// ---------------------------------------------------------------------------
// setup = prep (quantize weights, MFMA-fragment-major) + pad (zero X2 borders)
// fused into one launch. blocks 0..143 are prep, 144..599 are pad.
// ---------------------------------------------------------------------------
__global__ __launch_bounds__(256) void setup_kernel(
        const float* __restrict__ w1, const float* __restrict__ wa1,
        const float* __restrict__ w2, const float* __restrict__ wa2,
        f16* __restrict__ W2a, f16* __restrict__ W2b, char* __restrict__ X2) {
    const int idx = blockIdx.x * 256 + threadIdx.x;    // 0..153599
    if (idx < 36864) {
        // ---- prep: w -> integer-valued fp16, chunk (tap*16+k2)*128+oc ----
        const float* w;
        const float* wa;
        f16* o;
        int m;
        if (idx < 18432) { w = w1; wa = wa1; o = W2a; m = idx; }
        else             { w = w2; wa = wa2; o = W2b; m = idx - 18432; }
        const int tap = m >> 11;
        const int r = m & 2047;
        const int k2 = r >> 7;
        const int oc = r & 127;
        const float a = wa[tap];
        const float* src = w + ((size_t)(tap * 128 + oc) * 128 + k2 * 8);
        half8 hv;
#pragma unroll
        for (int j = 0; j < 8; ++j)
            hv[j] = (f16)rintf(fminf(fmaxf(src[j] / a, -4.f), 3.f));
        *(half8*)(o + (size_t)m * 8) = hv;
    } else {
        // ---- pad: zero the spatial border chunks of X2 ----
        const int m = idx - 36864;                     // 0..116735 = 32*16*228
        const int k2 = m / 3648;
        const int r = m - k2 * 3648;
        const int b = r / 228;
        const int j = r - b * 228;
        int h, w;
        if (j < 58)        { h = 0;  w = j; }
        else if (j < 116)  { h = 57; w = j - 58; }
        else { const int k = j - 116; h = 1 + (k >> 1); w = (k & 1) * 57; }
        const size_t chunk = (size_t)k2 * PPLANE + (size_t)b * PB + h * 58 + w;
        float4 z = {0.f, 0.f, 0.f, 0.f};
        *(float4*)(X2 + chunk * 16) = z;
    }
}

// ---------------------------------------------------------------------------
// pack: x fp32 [b][c][hw] -> X2 hi/lo fp16 chunks [k2][b][hp][wp].
// ---------------------------------------------------------------------------
__global__ __launch_bounds__(256) void pack_kernel(
        const float* __restrict__ x, char* __restrict__ X2,
        float* __restrict__ stats) {
    const int t = threadIdx.x;
    const int blk = blockIdx.x;                 // 784 tiles of 64 px
    if (blk == 0 && t < 512) stats[t] = 0.f;    // zero stats1+stats2
    const int b = blk / 49;
    const int p0 = (blk - b * 49) * 64;
    const int px = t & 63;
    const int cq = t >> 6;
    const int p = p0 + px;
    const int h = p / 56;
    const int w = p - h * 56;
    const size_t pp = (size_t)b * PB + (h + 1) * 58 + (w + 1);
    const float* xb = x + (size_t)b * 128 * HW_ + p;
#pragma unroll
    for (int s = 0; s < 4; ++s) {
        const int cg = s * 4 + cq;              // 0..15
        half8 hv, lv;
#pragma unroll
        for (int j = 0; j < 8; ++j) {
            const float v = xb[(size_t)(cg * 8 + j) * HW_];
            const f16 hh = (f16)v;
            hv[j] = hh;
            lv[j] = (f16)(v - (float)hh);
        }
        *(half8*)(X2 + ((size_t)cg * PPLANE + pp) * 16) = hv;
        *(half8*)(X2 + ((size_t)(cg + 16) * PPLANE + pp) * 16) = lv;
    }
}

// ---------------------------------------------------------------------------
// conv: barrier-free MFMA split-conv.
// Block = 256 thr = 4 waves, tile 128px x 64oc; wave = 64px x 32oc (2mt x 1nt).
// Grid = 784 (392 px-tiles x 2 oc-halves), XCD-swizzled so both oc-halves of a
// px-tile share an XCD (A re-reads hit local L2; ~3.2 MB/XCD working set).
// A: direct global, 4-deep register rotation (refill at s for s+4).
// B: 8 fragments held in regs per tap, read from L2; next tap's frag kf is
//    prefetched right after its last use (step 8+kf) = ~8-step lookahead.
// No LDS, no __syncthreads in the main loop -> waves free-run; quantize VALU
// of one wave overlaps MFMA of the other 2 waves/SIMD (3 blocks/CU resident).
// ---------------------------------------------------------------------------
__global__ __launch_bounds__(256, 3) void conv_kernel(
        const char* __restrict__ X2, const char* __restrict__ W2,
        const float* __restrict__ wav, const float* __restrict__ pav,
        float* __restrict__ cbuf, float* __restrict__ stats) {
    __shared__ float red[256];
    const int t = threadIdx.x;
    const int lane = t & 63;
    const int wv = t >> 6;
    const int wm = wv & 1, wn = wv >> 1;
    // 784 = 8 * 98 exact; consecutive blk (same px-tile pair) -> same XCD
    const int blk = (blockIdx.x & 7) * 98 + (blockIdx.x >> 3);
    const int pxt = blk >> 1;                   // 0..391
    const int oh = blk & 1;                     // oc half
    const int kh = lane >> 5, ln = lane & 31;
    const int ocb = oh * 64 + wn * 32;
    // per-lane B byte offset within a (tap,kf) fragment group
    const int bv = (kh * 128 + ocb + ln) << 4;

    // pixel bases for the wave's two 32-px m-tiles (tap0 shift dn = -59)
    int aoff[2];
#pragma unroll
    for (int mt = 0; mt < 2; ++mt) {
        const int gp = pxt * 128 + wm * 64 + mt * 32 + ln;
        const int b = gp / HW_;
        const int p = gp - b * HW_;
        const int h = p / 56;
        const int w = p - h * 56;
        aoff[mt] = ((b * PB + (h + 1) * 58 + (w + 1) - 59) + kh * PPLANE) << 4;
    }

    // prologue: tap0 B fragments (8) and A chunks 0..3
    half8 bfr[8];
#pragma unroll
    for (int kf = 0; kf < 8; ++kf)
        bfr[kf] = *(const half8*)(W2 + bv + kf * 4096);
    half8 afr[2][4];
#pragma unroll
    for (int c = 0; c < 4; ++c)
#pragma unroll
        for (int mt = 0; mt < 2; ++mt)
            afr[mt][c] = *(const half8*)(X2 + aoff[mt] + c * ASTRIDE);

    floatx16 facc[2];
#pragma unroll
    for (int mt = 0; mt < 2; ++mt)
#pragma unroll
        for (int r = 0; r < 16; ++r) facc[mt][r] = 0.f;

    for (int tap = 0; tap < 9; ++tap) {
        const float pak = pav[tap];
        const float s1 = wav[tap] / pak;
        // delta of dn between tap and tap+1: -115 after taps 2,5 else +58
        const int dd = (((tap == 2) | (tap == 5)) ? -115 : 58) << 4;
        const int aoffn0 = aoff[0] + dd;
        const int aoffn1 = aoff[1] + dd;
        const char* wnxt = W2 + (tap + 1) * 32768 + bv;

        floatx16 acc[2];
#pragma unroll
        for (int mt = 0; mt < 2; ++mt)
#pragma unroll
            for (int r = 0; r < 16; ++r) acc[mt][r] = 0.f;

#pragma unroll
        for (int s = 0; s < 16; ++s) {
            acc[0] = __builtin_amdgcn_mfma_f32_32x32x16_f16(
                afr[0][s & 3], bfr[s & 7], acc[0], 0, 0, 0);
            acc[1] = __builtin_amdgcn_mfma_f32_32x32x16_f16(
                afr[1][s & 3], bfr[s & 7], acc[1], 0, 0, 0);
            // A rotation refill: within-tap chunks 4..15, then next tap 0..3
            if (s < 12) {
                afr[0][s & 3] = *(const half8*)(X2 + aoff[0] + (s + 4) * ASTRIDE);
                afr[1][s & 3] = *(const half8*)(X2 + aoff[1] + (s + 4) * ASTRIDE);
            } else if (tap < 8) {
                afr[0][s & 3] = *(const half8*)(X2 + aoffn0 + (s - 12) * ASTRIDE);
                afr[1][s & 3] = *(const half8*)(X2 + aoffn1 + (s - 12) * ASTRIDE);
            }
            // B next-tap prefetch: frag kf = s-8, right after its last use
            if (tap < 8 && s >= 8)
                bfr[s - 8] = *(const half8*)(wnxt + (s - 8) * 4096);
        }

        // per-tap 8-bit LSQ quantize of the partial sum, accumulate
#pragma unroll
        for (int mt = 0; mt < 2; ++mt)
#pragma unroll
            for (int r = 0; r < 16; ++r) {
                const float q = rintf(
                    __builtin_amdgcn_fmed3f(acc[mt][r] * s1, -128.f, 127.f));
                facc[mt][r] = fmaf(q, pak, facc[mt][r]);
            }
        aoff[0] = aoffn0;
        aoff[1] = aoffn1;
    }

    // epilogue: cbuf [gp][oc] fp32  (32x32 C/D: row=(r&3)+8*(r>>2)+4*kh, col=ln)
    const int gpb = pxt * 128 + wm * 64;
#pragma unroll
    for (int mt = 0; mt < 2; ++mt)
#pragma unroll
        for (int r = 0; r < 16; ++r) {
            const int row = (r & 3) + 8 * (r >> 2) + 4 * kh;
            cbuf[(size_t)(gpb + mt * 32 + row) * 128 + ocb + ln] = facc[mt][r];
        }

    // fused BN stats (block covers 64 oc)
    float s = 0.f, q = 0.f;
#pragma unroll
    for (int mt = 0; mt < 2; ++mt)
#pragma unroll
        for (int r = 0; r < 16; ++r) {
            const float v = facc[mt][r];
            s += v;
            q = fmaf(v, v, q);
        }
    s += __shfl_xor(s, 32, 64);
    q += __shfl_xor(q, 32, 64);
    if (lane < 32) {
        const int ol = wn * 32 + lane;          // 0..63 within block
        red[ol * 2 + wm] = s;
        red[128 + ol * 2 + wm] = q;
    }
    __syncthreads();
    if (t < 64) {
        atomicAdd(&stats[oh * 64 + t], red[2 * t] + red[2 * t + 1]);
        atomicAdd(&stats[128 + oh * 64 + t],
                  red[128 + 2 * t] + red[128 + 2 * t + 1]);
    }
}

// ---------------------------------------------------------------------------
// bn_split: cbuf fp32 [gp][oc] -> bn+relu -> X2 hi/lo packed (conv2 input).
// ---------------------------------------------------------------------------
__global__ __launch_bounds__(256) void bn_split_kernel(
        const float* __restrict__ cbuf, const float* __restrict__ stats,
        const float* __restrict__ g, const float* __restrict__ bb,
        char* __restrict__ X2) {
    __shared__ float xs[8192];
    __shared__ float scs[128], shs[128];
    const int t = threadIdx.x;
    if (t < 128) {
        const float m = stats[t] * (1.f / NPC);
        const float var = stats[128 + t] * (1.f / NPC) - m * m;
        const float inv = 1.f / sqrtf(var + 1e-5f);
        const float sc = g[t] * inv;
        scs[t] = sc;
        shs[t] = bb[t] - m * sc;
    }
    __syncthreads();
    const int blk = blockIdx.x;                  // 784
#pragma unroll
    for (int i = 0; i < 8; ++i) {
        const int idx = i * 256 + t;
        const int px = idx >> 5;
        const int q = idx & 31;
        const float4 v = *(const float4*)&cbuf[(size_t)(blk * 64 + px) * 128 + q * 4];
        const float vv[4] = {v.x, v.y, v.z, v.w};
#pragma unroll
        for (int j = 0; j < 4; ++j) {
            const int c = q * 4 + j;
            xs[c * 64 + SW(c, px)] = fmaxf(fmaf(vv[j], scs[c], shs[c]), 0.f);
        }
    }
    __syncthreads();
    const int b = blk / 49;
    const int p0 = (blk - b * 49) * 64;
    const int px = t & 63;
    const int cq = t >> 6;
    const int p = p0 + px;
    const int h = p / 56;
    const int w = p - h * 56;
    const size_t pp = (size_t)b * PB + (h + 1) * 58 + (w + 1);
#pragma unroll
    for (int s = 0; s < 4; ++s) {
        const int cg = s * 4 + cq;
        half8 hv, lv;
#pragma unroll
        for (int j = 0; j < 8; ++j) {
            const int c = cg * 8 + j;
            const float v = xs[c * 64 + SW(c, px)];
            const f16 hh = (f16)v;
            hv[j] = hh;
            lv[j] = (f16)(v - (float)hh);
        }
        *(half8*)(X2 + ((size_t)cg * PPLANE + pp) * 16) = hv;
        *(half8*)(X2 + ((size_t)(cg + 16) * PPLANE + pp) * 16) = lv;
    }
}

// ---------------------------------------------------------------------------
// final: bn2 + residual add + relu, [gp][oc] -> [b][c][hw] via swizzled LDS
// ---------------------------------------------------------------------------
__global__ __launch_bounds__(256) void final_kernel(
        const float* __restrict__ cbuf, const float* __restrict__ stats,
        const float* __restrict__ g, const float* __restrict__ bb,
        const float* __restrict__ resid, float* __restrict__ out) {
    __shared__ float xs[8192];
    __shared__ float scs[128], shs[128];
    const int t = threadIdx.x;
    if (t < 128) {
        const float m = stats[t] * (1.f / NPC);
        const float var = stats[128 + t] * (1.f / NPC) - m * m;
        const float inv = 1.f / sqrtf(var + 1e-5f);
        const float sc = g[t] * inv;
        scs[t] = sc;
        shs[t] = bb[t] - m * sc;
    }
    __syncthreads();
    const int blk = blockIdx.x;                  // 784
#pragma unroll
    for (int i = 0; i < 8; ++i) {
        const int idx = i * 256 + t;
        const int px = idx >> 5;
        const int q = idx & 31;
        const float4 v = *(const float4*)&cbuf[(size_t)(blk * 64 + px) * 128 + q * 4];
        const float vv[4] = {v.x, v.y, v.z, v.w};
#pragma unroll
        for (int j = 0; j < 4; ++j) {
            const int c = q * 4 + j;
            xs[c * 64 + SW(c, px)] = fmaf(vv[j], scs[c], shs[c]);
        }
    }
    __syncthreads();
    const int b = blk / 49;
    const int p0 = (blk - b * 49) * 64;
    const int lane = t & 63, wq = t >> 6;
#pragma unroll
    for (int i = 0; i < 32; ++i) {
        const int c = i * 4 + wq;
        const float v = xs[c * 64 + SW(c, lane)];
        const size_t gi = (size_t)(b * 128 + c) * HW_ + p0 + lane;
        out[gi] = fmaxf(v + resid[gi], 0.f);
    }
}

// ---------------------------------------------------------------------------
extern "C" void kernel_launch(void* const* d_in, const int* in_sizes, int n_in,
                              void* d_out, int out_size, void* d_ws, size_t ws_size,
                              hipStream_t stream) {
    const float* x   = (const float*)d_in[0];
    const float* w1  = (const float*)d_in[1];
    const float* wa1 = (const float*)d_in[2];
    const float* pa1 = (const float*)d_in[3];
    const float* g1  = (const float*)d_in[4];
    const float* b1  = (const float*)d_in[5];
    const float* w2  = (const float*)d_in[6];
    const float* wa2 = (const float*)d_in[7];
    const float* pa2 = (const float*)d_in[8];
    const float* g2  = (const float*)d_in[9];
    const float* b2  = (const float*)d_in[10];
    float* out = (float*)d_out;

    // ws layout (bytes):
    //   X2    @ 0          : 27,557,888  (32 planes * 53824 chunks * 16 B)
    //   cbuf  @ 27,557,888 : 25,690,112
    //   W2a   @ 53,248,000 :    294,912
    //   W2b   @ 53,542,912 :    294,912
    //   stats @ 53,837,824 :      2,048  (stats1 256 f + stats2 256 f)
    char* ws = (char*)d_ws;
    char*  X2    = ws;
    float* cbuf  = (float*)(ws + 27557888);
    f16*   W2a   = (f16*)(ws + 53248000);
    f16*   W2b   = (f16*)(ws + 53542912);
    float* stats = (float*)(ws + 53837824);
    float* stats1 = stats;
    float* stats2 = stats + 256;

    hipLaunchKernelGGL(setup_kernel, dim3(600), dim3(256), 0, stream,
                       w1, wa1, w2, wa2, W2a, W2b, X2);
    hipLaunchKernelGGL(pack_kernel, dim3(784), dim3(256), 0, stream,
                       x, X2, stats);
    hipLaunchKernelGGL(conv_kernel, dim3(784), dim3(256), 0, stream,
                       X2, (const char*)W2a, wa1, pa1, cbuf, stats1);
    hipLaunchKernelGGL(bn_split_kernel, dim3(784), dim3(256), 0, stream,
                       cbuf, stats1, g1, b1, X2);
    hipLaunchKernelGGL(conv_kernel, dim3(784), dim3(256), 0, stream,
                       X2, (const char*)W2b, wa2, pa2, cbuf, stats2);
    hipLaunchKernelGGL(final_kernel, dim3(784), dim3(256), 0, stream,
                       cbuf, stats2, g2, b2, x, out);
}

// Round 2
// 224.120 us; speedup vs baseline: 1.6983x; 1.6983x over previous
//
#include <hip/hip_runtime.h>
#include <math.h>

typedef _Float16 f16;
typedef _Float16 half8 __attribute__((ext_vector_type(8)));
typedef float floatx16 __attribute__((ext_vector_type(16)));
typedef unsigned int u32;

#define HW_     3136
#define NPC     50176.0f
#define PB      3364            // 58*58 padded pixels per image
#define PPLANE  53824           // 16 images * PB (chunks per k2-plane)
#define ASTRIDE (2 * PPLANE * 16)   // bytes between s-steps (k2 += 2) = 1722368

// LDS scalar swizzle (conflict-free both phases; same as final_kernel, verified)
#define SW(c, px) (((px) + ((c) >> 2) + ((c) & 3) * 8) & 63)

// async 16B global->LDS copy (lane L lands at wave-uniform ldsbase + L*16)
typedef __attribute__((address_space(3))) u32 lds_u32;
typedef __attribute__((address_space(1))) u32 glb_u32;
__device__ __forceinline__ void async_copy16(const void* g, void* l) {
    __builtin_amdgcn_global_load_lds((const glb_u32*)g, (lds_u32*)l, 16, 0, 0);
}

// ---------------------------------------------------------------------------
// setup = prep (quantize weights, MFMA-fragment-major) + pad (zero X2 borders)
// fused into one launch. idx 0..36863 prep, rest pad.
// ---------------------------------------------------------------------------
__global__ __launch_bounds__(256) void setup_kernel(
        const float* __restrict__ w1, const float* __restrict__ wa1,
        const float* __restrict__ w2, const float* __restrict__ wa2,
        f16* __restrict__ W2a, f16* __restrict__ W2b, char* __restrict__ X2) {
    const int idx = blockIdx.x * 256 + threadIdx.x;    // 0..153599
    if (idx < 36864) {
        // ---- prep: w -> integer-valued fp16, chunk (tap*16+k2)*128+oc ----
        const float* w;
        const float* wa;
        f16* o;
        int m;
        if (idx < 18432) { w = w1; wa = wa1; o = W2a; m = idx; }
        else             { w = w2; wa = wa2; o = W2b; m = idx - 18432; }
        const int tap = m >> 11;
        const int r = m & 2047;
        const int k2 = r >> 7;
        const int oc = r & 127;
        const float a = wa[tap];
        const float* src = w + ((size_t)(tap * 128 + oc) * 128 + k2 * 8);
        half8 hv;
#pragma unroll
        for (int j = 0; j < 8; ++j)
            hv[j] = (f16)rintf(fminf(fmaxf(src[j] / a, -4.f), 3.f));
        *(half8*)(o + (size_t)m * 8) = hv;
    } else {
        // ---- pad: zero the spatial border chunks of X2 ----
        const int m = idx - 36864;                     // 0..116735 = 32*16*228
        const int k2 = m / 3648;
        const int r = m - k2 * 3648;
        const int b = r / 228;
        const int j = r - b * 228;
        int h, w;
        if (j < 58)        { h = 0;  w = j; }
        else if (j < 116)  { h = 57; w = j - 58; }
        else { const int k = j - 116; h = 1 + (k >> 1); w = (k & 1) * 57; }
        const size_t chunk = (size_t)k2 * PPLANE + (size_t)b * PB + h * 58 + w;
        float4 z = {0.f, 0.f, 0.f, 0.f};
        *(float4*)(X2 + chunk * 16) = z;
    }
}

// ---------------------------------------------------------------------------
// pack: x fp32 [b][c][hw] -> X2 hi/lo fp16 chunks [k2][b][hp][wp].
// ---------------------------------------------------------------------------
__global__ __launch_bounds__(256) void pack_kernel(
        const float* __restrict__ x, char* __restrict__ X2,
        float* __restrict__ stats) {
    const int t = threadIdx.x;
    const int blk = blockIdx.x;                 // 784 tiles of 64 px
    if (blk == 0 && t < 512) stats[t] = 0.f;    // zero stats1+stats2
    const int b = blk / 49;
    const int p0 = (blk - b * 49) * 64;
    const int px = t & 63;
    const int cq = t >> 6;
    const int p = p0 + px;
    const int h = p / 56;
    const int w = p - h * 56;
    const size_t pp = (size_t)b * PB + (h + 1) * 58 + (w + 1);
    const float* xb = x + (size_t)b * 128 * HW_ + p;
#pragma unroll
    for (int s = 0; s < 4; ++s) {
        const int cg = s * 4 + cq;              // 0..15
        half8 hv, lv;
#pragma unroll
        for (int j = 0; j < 8; ++j) {
            const float v = xb[(size_t)(cg * 8 + j) * HW_];
            const f16 hh = (f16)v;
            hv[j] = hh;
            lv[j] = (f16)(v - (float)hh);
        }
        *(half8*)(X2 + ((size_t)cg * PPLANE + pp) * 16) = hv;
        *(half8*)(X2 + ((size_t)(cg + 16) * PPLANE + pp) * 16) = lv;
    }
}

// ---------------------------------------------------------------------------
// conv: MFMA split-conv, verified lockstep structure (one barrier per tap,
// LDS double-buffered B staged one tap ahead via global_load_lds, A via
// 8-deep global register rotation with cross-tap refill).
// CHANGE vs 50us baseline: tile 64px x 128oc (was 128x128) -> grid 784
// (3.06 blocks/CU, dynamic backfill, no 1.53x static imbalance); wave is
// 32px x 64oc (mt dim removed); B ds_read rotation deepened 2->4 slots
// (covers ~120cyc LDS latency); quantize uses fmed3 (4 VALU ops/elem).
// L2 locality preserved: same XCD swizzle (contiguous px slab per XCD),
// same lockstep barriers, same total A issue volume.
// ---------------------------------------------------------------------------
__global__ __launch_bounds__(256, 2) void conv_kernel(
        const char* __restrict__ X2, const char* __restrict__ W2,
        const float* __restrict__ wav, const float* __restrict__ pav,
        float* __restrict__ cbuf, float* __restrict__ stats) {
    __shared__ f16 Bls[2][16384];    // 2 x 32 KB (chunk-major, W2 tap order)
    __shared__ float red[512];
    const int t = threadIdx.x;
    const int lane = t & 63;
    const int wv = t >> 6;
    const int wm = wv & 1, wn = wv >> 1;
    const int tile = (blockIdx.x & 7) * 98 + (blockIdx.x >> 3);  // 784 = 8*98
    const int kh = lane >> 5;
    const int ln = lane & 31;

    // pixel base for the wave's single 32-px m-tile
    const int gp = tile * 64 + wm * 32 + ln;
    const int b = gp / HW_;
    const int p = gp - b * HW_;
    const int h = p / 56;
    const int w = p - h * 56;
    const int ppad = b * PB + (h + 1) * 58 + (w + 1);

    // B ds_read byte offset (fragment kf at + kf*4096)
    int bdsoff[2];
#pragma unroll
    for (int nt = 0; nt < 2; ++nt)
        bdsoff[nt] = (kh * 128 + wn * 64 + nt * 32 + ln) * 16;
    // B staging chunk indices (8 wave-insts x 64 lanes = 512 chunks per wave)
    const int sbase = wv * 8;

    floatx16 facc[2];
#pragma unroll
    for (int nt = 0; nt < 2; ++nt)
#pragma unroll
        for (int r = 0; r < 16; ++r) facc[nt][r] = 0.f;

    // ---- prologue: stage tap0 B into buf0; fill A chunks 0..7 (tap0) ----
#pragma unroll
    for (int i = 0; i < 8; ++i)
        async_copy16(W2 + (((sbase + i) * 64 + lane) << 4),
                     (void*)&Bls[0][(sbase + i) * 512]);
    int aoff = ((ppad - 59) + kh * PPLANE) << 4;   // tap0: di=-1,dj=-1
    int aoffn = aoff;
    half8 afr[8];
#pragma unroll
    for (int s0 = 0; s0 < 8; ++s0)
        afr[s0] = *(const half8*)(X2 + aoff + s0 * ASTRIDE);
    __syncthreads();    // fences tap0 B staging

    for (int tap = 0; tap < 9; ++tap) {
        const float pak = pav[tap];
        const float s1 = wav[tap] / pak;
        const char* bcur = (const char*)&Bls[tap & 1][0];
        if (tap < 8) {
            // stage next tap's B into the other buffer (fenced by tap-end barrier)
            const char* wt = W2 + (tap + 1) * 32768;
            f16* bnxt = &Bls[(tap + 1) & 1][0];
#pragma unroll
            for (int i = 0; i < 8; ++i)
                async_copy16(wt + (((sbase + i) * 64 + lane) << 4),
                             (void*)&bnxt[(sbase + i) * 512]);
            const int dn = ((tap + 1) % 3 - 1) * 58 + ((tap + 1) / 3 - 1);
            aoffn = ((ppad + dn) + kh * PPLANE) << 4;
        }
        // prefill B slots for steps 0..3 (current buffer valid since barrier)
        half8 bds[2][4];
#pragma unroll
        for (int nt = 0; nt < 2; ++nt)
#pragma unroll
            for (int sl = 0; sl < 4; ++sl)
                bds[nt][sl] = *(const half8*)(bcur + sl * 4096 + bdsoff[nt]);

        floatx16 acc[2];
#pragma unroll
        for (int nt = 0; nt < 2; ++nt)
#pragma unroll
            for (int r = 0; r < 16; ++r) acc[nt][r] = 0.f;

#pragma unroll
        for (int s = 0; s < 16; ++s) {
            acc[0] = __builtin_amdgcn_mfma_f32_32x32x16_f16(
                afr[s & 7], bds[0][s & 3], acc[0], 0, 0, 0);
            acc[1] = __builtin_amdgcn_mfma_f32_32x32x16_f16(
                afr[s & 7], bds[1][s & 3], acc[1], 0, 0, 0);
            // B rotation refill: slot used at step s+4 (kf (s+4)&7)
            if (s <= 11) {
                const int kf4 = (s + 4) & 7;
#pragma unroll
                for (int nt = 0; nt < 2; ++nt)
                    bds[nt][s & 3] =
                        *(const half8*)(bcur + kf4 * 4096 + bdsoff[nt]);
            }
            // A rotation refill: within-tap chunks 8..15, then next tap 0..7
            if (s < 8) {
                afr[s & 7] = *(const half8*)(X2 + aoff + (s + 8) * ASTRIDE);
            } else if (tap < 8) {
                afr[s & 7] = *(const half8*)(X2 + aoffn + (s - 8) * ASTRIDE);
            }
        }

        // per-tap 8-bit LSQ quantize of the partial sum, accumulate
#pragma unroll
        for (int nt = 0; nt < 2; ++nt)
#pragma unroll
            for (int r = 0; r < 16; ++r) {
                const float q = rintf(
                    __builtin_amdgcn_fmed3f(acc[nt][r] * s1, -128.f, 127.f));
                facc[nt][r] = fmaf(q, pak, facc[nt][r]);
            }
        aoff = aoffn;
        __syncthreads();   // all reads of buf[tap&1] done; fences next-B staging
    }

    // epilogue: cbuf [gp][oc] fp32  (32x32 C/D: row=(r&3)+8*(r>>2)+4*kh, col=ln)
    const int gpb = tile * 64 + wm * 32;
#pragma unroll
    for (int r = 0; r < 16; ++r) {
        const int row = (r & 3) + 8 * (r >> 2) + 4 * kh;
        float* rp = cbuf + (size_t)(gpb + row) * 128 + wn * 64 + ln;
        rp[0]  = facc[0][r];
        rp[32] = facc[1][r];
    }

    // fused BN stats
    float sv[2], qv[2];
#pragma unroll
    for (int nt = 0; nt < 2; ++nt) {
        float s = 0.f, q = 0.f;
#pragma unroll
        for (int r = 0; r < 16; ++r) {
            const float v = facc[nt][r];
            s += v;
            q = fmaf(v, v, q);
        }
        s += __shfl_xor(s, 32, 64);
        q += __shfl_xor(q, 32, 64);
        sv[nt] = s; qv[nt] = q;
    }
    if (lane < 32) {
#pragma unroll
        for (int nt = 0; nt < 2; ++nt) {
            const int oc = wn * 64 + nt * 32 + lane;
            red[oc * 2 + wm] = sv[nt];
            red[256 + oc * 2 + wm] = qv[nt];
        }
    }
    __syncthreads();
    if (t < 128) {
        atomicAdd(&stats[t],       red[2 * t] + red[2 * t + 1]);
        atomicAdd(&stats[128 + t], red[256 + 2 * t] + red[256 + 2 * t + 1]);
    }
}

// ---------------------------------------------------------------------------
// bn_split: cbuf fp32 [gp][oc] -> bn+relu -> X2 hi/lo packed (conv2 input).
// ---------------------------------------------------------------------------
__global__ __launch_bounds__(256) void bn_split_kernel(
        const float* __restrict__ cbuf, const float* __restrict__ stats,
        const float* __restrict__ g, const float* __restrict__ bb,
        char* __restrict__ X2) {
    __shared__ float xs[8192];
    __shared__ float scs[128], shs[128];
    const int t = threadIdx.x;
    if (t < 128) {
        const float m = stats[t] * (1.f / NPC);
        const float var = stats[128 + t] * (1.f / NPC) - m * m;
        const float inv = 1.f / sqrtf(var + 1e-5f);
        const float sc = g[t] * inv;
        scs[t] = sc;
        shs[t] = bb[t] - m * sc;
    }
    __syncthreads();
    const int blk = blockIdx.x;                  // 784
#pragma unroll
    for (int i = 0; i < 8; ++i) {
        const int idx = i * 256 + t;
        const int px = idx >> 5;
        const int q = idx & 31;
        const float4 v = *(const float4*)&cbuf[(size_t)(blk * 64 + px) * 128 + q * 4];
        const float vv[4] = {v.x, v.y, v.z, v.w};
#pragma unroll
        for (int j = 0; j < 4; ++j) {
            const int c = q * 4 + j;
            xs[c * 64 + SW(c, px)] = fmaxf(fmaf(vv[j], scs[c], shs[c]), 0.f);
        }
    }
    __syncthreads();
    const int b = blk / 49;
    const int p0 = (blk - b * 49) * 64;
    const int px = t & 63;
    const int cq = t >> 6;
    const int p = p0 + px;
    const int h = p / 56;
    const int w = p - h * 56;
    const size_t pp = (size_t)b * PB + (h + 1) * 58 + (w + 1);
#pragma unroll
    for (int s = 0; s < 4; ++s) {
        const int cg = s * 4 + cq;
        half8 hv, lv;
#pragma unroll
        for (int j = 0; j < 8; ++j) {
            const int c = cg * 8 + j;
            const float v = xs[c * 64 + SW(c, px)];
            const f16 hh = (f16)v;
            hv[j] = hh;
            lv[j] = (f16)(v - (float)hh);
        }
        *(half8*)(X2 + ((size_t)cg * PPLANE + pp) * 16) = hv;
        *(half8*)(X2 + ((size_t)(cg + 16) * PPLANE + pp) * 16) = lv;
    }
}

// ---------------------------------------------------------------------------
// final: bn2 + residual add + relu, [gp][oc] -> [b][c][hw] via swizzled LDS
// ---------------------------------------------------------------------------
__global__ __launch_bounds__(256) void final_kernel(
        const float* __restrict__ cbuf, const float* __restrict__ stats,
        const float* __restrict__ g, const float* __restrict__ bb,
        const float* __restrict__ resid, float* __restrict__ out) {
    __shared__ float xs[8192];
    __shared__ float scs[128], shs[128];
    const int t = threadIdx.x;
    if (t < 128) {
        const float m = stats[t] * (1.f / NPC);
        const float var = stats[128 + t] * (1.f / NPC) - m * m;
        const float inv = 1.f / sqrtf(var + 1e-5f);
        const float sc = g[t] * inv;
        scs[t] = sc;
        shs[t] = bb[t] - m * sc;
    }
    __syncthreads();
    const int blk = blockIdx.x;                  // 784
#pragma unroll
    for (int i = 0; i < 8; ++i) {
        const int idx = i * 256 + t;
        const int px = idx >> 5;
        const int q = idx & 31;
        const float4 v = *(const float4*)&cbuf[(size_t)(blk * 64 + px) * 128 + q * 4];
        const float vv[4] = {v.x, v.y, v.z, v.w};
#pragma unroll
        for (int j = 0; j < 4; ++j) {
            const int c = q * 4 + j;
            xs[c * 64 + SW(c, px)] = fmaf(vv[j], scs[c], shs[c]);
        }
    }
    __syncthreads();
    const int b = blk / 49;
    const int p0 = (blk - b * 49) * 64;
    const int lane = t & 63, wq = t >> 6;
#pragma unroll
    for (int i = 0; i < 32; ++i) {
        const int c = i * 4 + wq;
        const float v = xs[c * 64 + SW(c, lane)];
        const size_t gi = (size_t)(b * 128 + c) * HW_ + p0 + lane;
        out[gi] = fmaxf(v + resid[gi], 0.f);
    }
}

// ---------------------------------------------------------------------------
extern "C" void kernel_launch(void* const* d_in, const int* in_sizes, int n_in,
                              void* d_out, int out_size, void* d_ws, size_t ws_size,
                              hipStream_t stream) {
    const float* x   = (const float*)d_in[0];
    const float* w1  = (const float*)d_in[1];
    const float* wa1 = (const float*)d_in[2];
    const float* pa1 = (const float*)d_in[3];
    const float* g1  = (const float*)d_in[4];
    const float* b1  = (const float*)d_in[5];
    const float* w2  = (const float*)d_in[6];
    const float* wa2 = (const float*)d_in[7];
    const float* pa2 = (const float*)d_in[8];
    const float* g2  = (const float*)d_in[9];
    const float* b2  = (const float*)d_in[10];
    float* out = (float*)d_out;

    // ws layout (bytes):
    //   X2    @ 0          : 27,557,888  (32 planes * 53824 chunks * 16 B)
    //   cbuf  @ 27,557,888 : 25,690,112
    //   W2a   @ 53,248,000 :    294,912
    //   W2b   @ 53,542,912 :    294,912
    //   stats @ 53,837,824 :      2,048  (stats1 256 f + stats2 256 f)
    char* ws = (char*)d_ws;
    char*  X2    = ws;
    float* cbuf  = (float*)(ws + 27557888);
    f16*   W2a   = (f16*)(ws + 53248000);
    f16*   W2b   = (f16*)(ws + 53542912);
    float* stats = (float*)(ws + 53837824);
    float* stats1 = stats;
    float* stats2 = stats + 256;

    hipLaunchKernelGGL(setup_kernel, dim3(600), dim3(256), 0, stream,
                       w1, wa1, w2, wa2, W2a, W2b, X2);
    hipLaunchKernelGGL(pack_kernel, dim3(784), dim3(256), 0, stream,
                       x, X2, stats);
    hipLaunchKernelGGL(conv_kernel, dim3(784), dim3(256), 0, stream,
                       X2, (const char*)W2a, wa1, pa1, cbuf, stats1);
    hipLaunchKernelGGL(bn_split_kernel, dim3(784), dim3(256), 0, stream,
                       cbuf, stats1, g1, b1, X2);
    hipLaunchKernelGGL(conv_kernel, dim3(784), dim3(256), 0, stream,
                       X2, (const char*)W2b, wa2, pa2, cbuf, stats2);
    hipLaunchKernelGGL(final_kernel, dim3(784), dim3(256), 0, stream,
                       cbuf, stats2, g2, b2, x, out);
}